// Round 16
// baseline (3083.882 us; speedup 1.0000x reference)
//
#include <hip/hip_runtime.h>
#include <hip/hip_fp16.h>
#include <cmath>

#define RN 512
#define RT 1024
#define RB 64
#define SMEM_BYTES (131072 + 1024)  // 128KB W + ownpk(512B) + ctl; 2x > 160KB -> 1 block/CU

typedef _Float16 half2v __attribute__((ext_vector_type(2)));

__device__ __forceinline__ float fast_tanh(float x) {
    float e = __expf(2.0f * x);
    return 1.0f - 2.0f / (e + 1.0f);
}
__device__ __forceinline__ unsigned pack2(float a, float b) {   // RNE
    return (unsigned)__half_as_ushort(__float2half(a)) |
           ((unsigned)__half_as_ushort(__float2half(b)) << 16);
}
__device__ __forceinline__ unsigned pkrtz(float a, float b) {   // 1-instr pack
    auto h = __builtin_amdgcn_cvt_pkrtz(a, b);
    return __builtin_bit_cast(unsigned, h);
}
__device__ __forceinline__ float dot2(unsigned wa, unsigned tb, float acc) {
    half2v a = __builtin_bit_cast(half2v, wa);
    half2v b = __builtin_bit_cast(half2v, tb);
    return __builtin_amdgcn_fdot2(a, b, acc, false);
}
// VALU cross-lane add via DPP; ctrl must be an ICE -> template.
template <int CTRL>
__device__ __forceinline__ float dpp_add(float x) {
    int p = __builtin_amdgcn_update_dpp(0, __float_as_int(x), CTRL, 0xf, 0xf, true);
    return x + __int_as_float(p);
}
__device__ __forceinline__ float red16(float x) {
    x = dpp_add<0xB1>(x);   // quad_perm xor1
    x = dpp_add<0x4E>(x);   // quad_perm xor2
    x = dpp_add<0x141>(x);  // row_half_mirror
    x = dpp_add<0x140>(x);  // row_mirror
    return x;
}
#define D2Q(acc, wq, tq) \
    acc = dot2((wq).x, (tq).x, acc); acc = dot2((wq).y, (tq).y, acc); \
    acc = dot2((wq).z, (tq).z, acc); acc = dot2((wq).w, (tq).w, acc);

// R15 skeleton (proven 2034us, 0 conflicts) + BATCH PAIRING: each same-XCD
// quad serves batches (pair, pair+32) with ONE shared W pass -- the 16 W
// ds_read_b128/thread/step feed BOTH batches' dots (LDS bytes and the whole
// sync chain amortize 2x per batch-step). 32 pairs x 4 parts = 128 working
// blocks; we still launch 256 cooperative blocks (131KB LDS forces exactly
// 32 resident/XCD, keeping the XCC_ID+rank math exact) and ranks >=16 per
// XCD exit immediately. Fan stays 4 (R7: 8-fan regressed). Protocol
// unchanged: phase A before the relaxed tid0 poll, one broadcast barrier,
// fp32-outH exchange (fresh addresses -- the only proven channel), DPP
// reduce, per-wave vmcnt drain -> LDS arrival -> 8th wave signals, bottom
// barrier for ownpk coherence.
__global__ void __launch_bounds__(512, 1) rnn_step_kernel(
    const float* __restrict__ h0,
    const float* __restrict__ X,
    const uint4* __restrict__ Wpk,     // [4 part][4 band][4 i][512 tid]
    const float* __restrict__ tanh0,
    float* __restrict__ outH,
    unsigned* __restrict__ ctr,
    unsigned* __restrict__ xcdctr)
{
    extern __shared__ unsigned char smem[];
    uint4*    Wl    = (uint4*)smem;                  // 8192 uint4 = 128 KB
    unsigned* ownpk = (unsigned*)(smem + 131072);    // [2 batch][64] u32 pairs
    int*      bc    = (int*)(smem + 131072 + 512);
    unsigned* lctr  = (unsigned*)(smem + 131072 + 528);

    const int tid = threadIdx.x;
    if (tid == 0) {
        unsigned xcd;
        asm volatile("s_getreg_b32 %0, hwreg(HW_REG_XCC_ID)" : "=s"(xcd));
        xcd &= 7u;
        unsigned rank = __hip_atomic_fetch_add(&xcdctr[xcd], 1u,
                            __ATOMIC_RELAXED, __HIP_MEMORY_SCOPE_AGENT) & 31u;
        if (rank < 16u) {
            int slot = (int)(xcd * 16u + rank);   // 0..127
            bc[0] = slot >> 2;                    // pair 0..31
            bc[1] = slot & 3;                     // part 0..3
            bc[2] = 1;
        } else {
            bc[2] = 0;                            // surplus block: exit
        }
        *lctr = 0u;
    }
    __syncthreads();
    if (bc[2] == 0) return;                       // wave-uniform block exit
    const int pair = bc[0], part = bc[1];
    const int bA = pair, bB = pair + 32;

    // stage our part's W slice (pre-permuted read order): straight copy
    {
        const uint4* src = Wpk + part * 8192;
        #pragma unroll
        for (int i = 0; i < 16; ++i)
            Wl[i * 512 + tid] = src[i * 512 + tid];
    }

    const int rg = tid >> 4;                  // 0..31 : 4-row group
    const int kc = tid & 15;                  // 0..15 : 8-k sub-chunk per band
    const int row0 = part * 128 + rg * 4;

    float4 hA = {0,0,0,0}, hB = {0,0,0,0};
    float4 xvA = {0,0,0,0}, xvB = {0,0,0,0};
    if (kc == 0) {
        hA = *reinterpret_cast<const float4*>(h0 + row0);
        hB = hA;
        float t0 = tanhf(hA.x), t1 = tanhf(hA.y), t2 = tanhf(hA.z), t3 = tanhf(hA.w);
        ownpk[2 * rg]          = pack2(t0, t1);   // batch A slot
        ownpk[2 * rg + 1]      = pack2(t2, t3);
        ownpk[64 + 2 * rg]     = pack2(t0, t1);   // batch B slot (same h0)
        ownpk[64 + 2 * rg + 1] = pack2(t2, t3);
        xvA = *reinterpret_cast<const float4*>(&X[(size_t)bA * RT * RN + row0]);
        xvB = *reinterpret_cast<const float4*>(&X[(size_t)bB * RT * RN + row0]);
    }

    unsigned* gctr = ctr + pair * 32;         // 128B line per pair
    __syncthreads();                          // W + ownpk staged

    #pragma unroll 1
    for (int t = 0; t < RT; ++t) {
        // ---- 2-deep X prefetch for both batches ----
        float4 xnA = {0,0,0,0}, xnB = {0,0,0,0};
        if (kc == 0) {
            const int tn = (t + 1 < RT) ? t + 1 : t;
            xnA = *reinterpret_cast<const float4*>(&X[((size_t)bA * RT + tn) * RN + row0]);
            xnB = *reinterpret_cast<const float4*>(&X[((size_t)bB * RT + tn) * RN + row0]);
        }

        // ---- phase A: own band, both batches (W reads shared) ----
        float aA0 = 0.f, aA1 = 0.f, aA2 = 0.f, aA3 = 0.f;
        float aB0 = 0.f, aB1 = 0.f, aB2 = 0.f, aB3 = 0.f;
        {
            uint4 thA = *reinterpret_cast<const uint4*>(&ownpk[4 * kc]);
            uint4 thB = *reinterpret_cast<const uint4*>(&ownpk[64 + 4 * kc]);
            uint4 wq0 = Wl[(part * 4 + 0) * 512 + tid];
            uint4 wq1 = Wl[(part * 4 + 1) * 512 + tid];
            uint4 wq2 = Wl[(part * 4 + 2) * 512 + tid];
            uint4 wq3 = Wl[(part * 4 + 3) * 512 + tid];
            D2Q(aA0, wq0, thA) D2Q(aA1, wq1, thA) D2Q(aA2, wq2, thA) D2Q(aA3, wq3, thA)
            D2Q(aB0, wq0, thB) D2Q(aB1, wq1, thB) D2Q(aB2, wq2, thB) D2Q(aB3, wq3, thB)
        }

        // ---- wait for all 4 parts of step t-1 (tid0 poll + barrier bcast) ----
        if (tid == 0 && t > 0) {
            const unsigned tgt = 4u * (unsigned)t;
            while (__hip_atomic_load(gctr, __ATOMIC_RELAXED,
                                     __HIP_MEMORY_SCOPE_AGENT) < tgt)
                __builtin_amdgcn_s_sleep(1);
        }
        __syncthreads();

        // ---- phase B: 3 partner bands x 2 batches (W reads shared) ----
        const float* srcA = (t == 0) ? tanh0 : &outH[((size_t)bA * RT + (t - 1)) * RN];
        const float* srcB = (t == 0) ? tanh0 : &outH[((size_t)bB * RT + (t - 1)) * RN];
        #pragma unroll
        for (int bb = 0; bb < 3; ++bb) {
            const int b = bb + (bb >= part);
            const int ko = b * 128 + kc * 8;
            float4 fA0 = *reinterpret_cast<const float4*>(srcA + ko);
            float4 fA1 = *reinterpret_cast<const float4*>(srcA + ko + 4);
            float4 fB0 = *reinterpret_cast<const float4*>(srcB + ko);
            float4 fB1 = *reinterpret_cast<const float4*>(srcB + ko + 4);
            uint4 tvA = make_uint4(pkrtz(fA0.x, fA0.y), pkrtz(fA0.z, fA0.w),
                                   pkrtz(fA1.x, fA1.y), pkrtz(fA1.z, fA1.w));
            uint4 tvB = make_uint4(pkrtz(fB0.x, fB0.y), pkrtz(fB0.z, fB0.w),
                                   pkrtz(fB1.x, fB1.y), pkrtz(fB1.z, fB1.w));
            uint4 wq0 = Wl[(b * 4 + 0) * 512 + tid];
            uint4 wq1 = Wl[(b * 4 + 1) * 512 + tid];
            uint4 wq2 = Wl[(b * 4 + 2) * 512 + tid];
            uint4 wq3 = Wl[(b * 4 + 3) * 512 + tid];
            D2Q(aA0, wq0, tvA) D2Q(aA1, wq1, tvA) D2Q(aA2, wq2, tvA) D2Q(aA3, wq3, tvA)
            D2Q(aB0, wq0, tvB) D2Q(aB1, wq1, tvB) D2Q(aB2, wq2, tvB) D2Q(aB3, wq3, tvB)
        }

        // ---- 16-lane all-reduce in VALU (DPP) ----
        aA0 = red16(aA0); aA1 = red16(aA1); aA2 = red16(aA2); aA3 = red16(aA3);
        aB0 = red16(aB0); aB1 = red16(aB1); aB2 = red16(aB2); aB3 = red16(aB3);

        if (kc == 0) {
            hA.x = 0.9f * hA.x + 0.1f * (aA0 + xvA.x);
            hA.y = 0.9f * hA.y + 0.1f * (aA1 + xvA.y);
            hA.z = 0.9f * hA.z + 0.1f * (aA2 + xvA.z);
            hA.w = 0.9f * hA.w + 0.1f * (aA3 + xvA.w);
            hB.x = 0.9f * hB.x + 0.1f * (aB0 + xvB.x);
            hB.y = 0.9f * hB.y + 0.1f * (aB1 + xvB.y);
            hB.z = 0.9f * hB.z + 0.1f * (aB2 + xvB.z);
            hB.w = 0.9f * hB.w + 0.1f * (aB3 + xvB.w);
            float a0 = fast_tanh(hA.x), a1 = fast_tanh(hA.y);
            float a2 = fast_tanh(hA.z), a3 = fast_tanh(hA.w);
            float b0 = fast_tanh(hB.x), b1 = fast_tanh(hB.y);
            float b2 = fast_tanh(hB.z), b3 = fast_tanh(hB.w);
            *reinterpret_cast<float4*>(&outH[((size_t)bA * RT + t) * RN + row0]) =
                make_float4(a0, a1, a2, a3);
            *reinterpret_cast<float4*>(&outH[((size_t)bB * RT + t) * RN + row0]) =
                make_float4(b0, b1, b2, b3);
            ownpk[2 * rg]          = pack2(a0, a1);
            ownpk[2 * rg + 1]      = pack2(a2, a3);
            ownpk[64 + 2 * rg]     = pack2(b0, b1);
            ownpk[64 + 2 * rg + 1] = pack2(b2, b3);
        }

        // ---- signal hoist: per-wave drain -> LDS arrival -> 8th wave fires ----
        asm volatile("s_waitcnt vmcnt(0)" ::: "memory");
        if ((tid & 63) == 0) {
            unsigned a = __hip_atomic_fetch_add(lctr, 1u, __ATOMIC_RELAXED,
                                                __HIP_MEMORY_SCOPE_WORKGROUP);
            if ((a & 7u) == 7u)
                __hip_atomic_fetch_add(gctr, 1u, __ATOMIC_RELAXED,
                                       __HIP_MEMORY_SCOPE_AGENT);
        }
        __syncthreads();   // ownpk coherence for next step's phase A
        xvA = xnA; xvB = xnB;
    }
}

// one-time: W -> f16 pairs in exact per-read order
// Wpk[part*8192 + (b*4+i)*512 + tid] = W[part*128+(tid>>4)*4+i][b*128+(tid&15)*8 ..+8]
__global__ void pack_w(const float* __restrict__ W, uint4* __restrict__ Wpk)
{
    int o = blockIdx.x * blockDim.x + threadIdx.x;
    if (o >= 32768) return;
    int part = o >> 13;
    int b    = (o >> 11) & 3;
    int i    = (o >> 9) & 3;
    int tid  = o & 511;
    int row  = part * 128 + (tid >> 4) * 4 + i;
    int k0   = b * 128 + (tid & 15) * 8;
    const float* s = W + (size_t)row * RN + k0;
    uint4 v;
    v.x = pack2(s[0], s[1]); v.y = pack2(s[2], s[3]);
    v.z = pack2(s[4], s[5]); v.w = pack2(s[6], s[7]);
    Wpk[o] = v;
}

// geometry epilogue: geo[b,t,:] = hidden[b,t,:] @ Gw^T + Gb ; one wave per (b,t)
__global__ void geom_kernel(const float* __restrict__ hid,
                            const float* __restrict__ Gw,
                            const float* __restrict__ Gb,
                            float* __restrict__ geo)
{
    const int wid  = (blockIdx.x * blockDim.x + threadIdx.x) >> 6;
    const int lane = threadIdx.x & 63;
    if (wid >= RB * RT) return;
    const float* rowp = hid + (size_t)wid * RN;
    float g0 = 0.f, g1 = 0.f;
    #pragma unroll
    for (int j = 0; j < 8; ++j) {
        float v = rowp[lane + 64 * j];
        g0 = fmaf(v, Gw[lane + 64 * j], g0);
        g1 = fmaf(v, Gw[RN + lane + 64 * j], g1);
    }
    #pragma unroll
    for (int m = 32; m >= 1; m >>= 1) {
        g0 += __shfl_xor(g0, m);
        g1 += __shfl_xor(g1, m);
    }
    if (lane == 0) {
        geo[(size_t)wid * 2]     = g0 + Gb[0];
        geo[(size_t)wid * 2 + 1] = g1 + Gb[1];
    }
}

// per-launch init: tanh(h0) table + zero counters (ws poisoned once, never
// re-poisoned -> re-init every call; deterministic)
__global__ void init_misc(const float* __restrict__ h0,
                          float* __restrict__ tanh0,
                          unsigned* __restrict__ ctr,
                          unsigned* __restrict__ xcdctr)
{
    int i = blockIdx.x * blockDim.x + threadIdx.x;
    if (i < RN) tanh0[i] = tanhf(h0[i]);
    if (i < 32 * 32) ctr[i] = 0u;
    if (i < 8) xcdctr[i] = 0u;
}

extern "C" void kernel_launch(void* const* d_in, const int* in_sizes, int n_in,
                              void* d_out, int out_size, void* d_ws, size_t ws_size,
                              hipStream_t stream)
{
    const float* h0 = (const float*)d_in[0];
    const float* X  = (const float*)d_in[1];
    const float* W  = (const float*)d_in[2];
    const float* Gw = (const float*)d_in[3];
    const float* Gb = (const float*)d_in[4];

    float* outH = (float*)d_out;
    float* geo  = outH + (size_t)RB * RT * RN;

    float*    tanh0  = (float*)d_ws;                  // 512 f32
    unsigned* ctr    = (unsigned*)d_ws + RN;          // 32*32 u32
    unsigned* xcdctr = ctr + 32 * 32;                 // 8 u32
    uint4*    Wpk    = (uint4*)(((uintptr_t)(xcdctr + 8) + 15) & ~(uintptr_t)15);

    (void)hipFuncSetAttribute((const void*)rnn_step_kernel,
                              hipFuncAttributeMaxDynamicSharedMemorySize, SMEM_BYTES);

    pack_w<<<64, 512, 0, stream>>>(W, Wpk);
    init_misc<<<8, 512, 0, stream>>>(h0, tanh0, ctr, xcdctr);

    void* kargs[] = { (void*)&h0, (void*)&X, (void*)&Wpk, (void*)&tanh0,
                      (void*)&outH, (void*)&ctr, (void*)&xcdctr };
    (void)hipLaunchCooperativeKernel(rnn_step_kernel, dim3(256), dim3(512),
                                     kargs, SMEM_BYTES, stream);

    geom_kernel<<<(RB * RT * 64 + 255) / 256, 256, 0, stream>>>(outH, Gw, Gb, geo);
}

// Round 18
// 2540.233 us; speedup vs baseline: 1.2140x; 1.2140x over previous
//
#include <hip/hip_runtime.h>
#include <hip/hip_fp16.h>
#include <cmath>

#define RN 512
#define RT 1024
#define RB 64
#define SMEM_BYTES 131872   // 128KB W + ownpk(256B) + ownpart(512B) + ctl; 1 block/CU

typedef _Float16 half2v __attribute__((ext_vector_type(2)));

__device__ __forceinline__ float fast_tanh(float x) {
    float e = __expf(2.0f * x);
    return 1.0f - 2.0f / (e + 1.0f);
}
__device__ __forceinline__ unsigned pack2(float a, float b) {   // RNE
    return (unsigned)__half_as_ushort(__float2half(a)) |
           ((unsigned)__half_as_ushort(__float2half(b)) << 16);
}
__device__ __forceinline__ float dot2(unsigned wa, unsigned tb, float acc) {
    half2v a = __builtin_bit_cast(half2v, wa);
    half2v b = __builtin_bit_cast(half2v, tb);
    return __builtin_amdgcn_fdot2(a, b, acc, false);
}
#define D2Q(acc, wq, tq) \
    acc = dot2((wq).x, (tq).x, acc); acc = dot2((wq).y, (tq).y, acc); \
    acc = dot2((wq).z, (tq).z, acc); acc = dot2((wq).w, (tq).w, acc);

// PARTIAL-DOT EXCHANGE, take 2. Same structure as round 17 (column-split W:
// block holds W[0:512, 128p:+128); the ENTIRE 64-dot2/thread matvec is
// partner-independent phase A because it needs only OWN rows' tanh), but the
// exchanged partials are now FP32 PAIRS via 64-bit RELAXED AGENT ATOMIC
// store/load -- zero extra rounding (fp32 accumulation end-to-end, exactly
// the R13/R15 numerics that measured absmax 0.125), and both sides of the
// exchange execute at the L2 coherence point (the same mechanism as the
// proven counter poll), so the depth-2 ring cannot be served stale L1 data.
// Ring depth-2 safety: bump(t+1) is bottom-barrier-ordered after tail(t), and
// a writer reaches scatter(t+2) only after poll(t+1) observed all bumps(t+1),
// so slot t&1 has no readers when overwritten. NO acquires anywhere (round-8
// lesson); same-XCD quads via XCC_ID + arrival rank (R13-proven mapping).
__global__ void __launch_bounds__(512, 1) rnn_step_kernel(
    const float* __restrict__ h0,
    const float* __restrict__ X,
    const uint4* __restrict__ Wpk,              // [4 part][16 j][512 tid]
    float* __restrict__ outH,
    unsigned long long* __restrict__ exch,      // [64 b][2 slot][4 dest][3 src][64]
    unsigned* __restrict__ ctr,
    unsigned* __restrict__ xcdctr)
{
    extern __shared__ unsigned char smem[];
    uint4*    Wl      = (uint4*)smem;                    // 8192 uint4 = 128 KB
    unsigned* ownpk   = (unsigned*)(smem + 131072);      // 64 u32: packed th pairs
    float*    ownpart = (float*)(smem + 131072 + 256);   // 128 f32: own partials
    int*      bc      = (int*)(smem + 131072 + 768);
    unsigned* lctr    = (unsigned*)(smem + 131072 + 776);

    const int tid = threadIdx.x;
    if (tid == 0) {
        unsigned xcd;
        asm volatile("s_getreg_b32 %0, hwreg(HW_REG_XCC_ID)" : "=s"(xcd));
        xcd &= 7u;
        unsigned rank = __hip_atomic_fetch_add(&xcdctr[xcd], 1u,
                            __ATOMIC_RELAXED, __HIP_MEMORY_SCOPE_AGENT) & 31u;
        int slot = (int)(xcd * 32u + rank);   // 0..255
        bc[0] = slot >> 2;                    // batch 0..63
        bc[1] = slot & 3;                     // part  0..3
        *lctr = 0u;
    }
    __syncthreads();
    const int batch = bc[0], part = bc[1];

    // stage column-slice W (pre-permuted read order): straight copy
    {
        const uint4* src = Wpk + part * 8192;
        #pragma unroll
        for (int i = 0; i < 16; ++i)
            Wl[i * 512 + tid] = src[i * 512 + tid];
    }

    // tail state: wave 0, thread tid<64 owns rows (128p+2tid, +1)
    float2 hreg = {0.f, 0.f}, xv = {0.f, 0.f};
    if (tid < 64) {
        hreg = *reinterpret_cast<const float2*>(h0 + part * 128 + 2 * tid);
        ownpk[tid] = pack2(tanhf(hreg.x), tanhf(hreg.y));
        xv = *reinterpret_cast<const float2*>(
            X + (size_t)batch * RT * RN + part * 128 + 2 * tid);
    }

    unsigned* gctr = ctr + batch * 32;        // 128B line per quad
    __syncthreads();                          // W + ownpk staged

    #pragma unroll 1
    for (int t = 0; t < RT; ++t) {
        // 2-deep x prefetch (wave 0)
        float2 xn = {0.f, 0.f};
        if (tid < 64) {
            const int tn = (t + 1 < RT) ? t + 1 : t;
            xn = *reinterpret_cast<const float2*>(
                X + ((size_t)batch * RT + tn) * RN + part * 128 + 2 * tid);
        }

        // ---- phase A (ALL dot work, partner-independent): full 128-k band
        //      dot for global row `tid`; th broadcast from ownpk ----
        float acc = 0.f;
        {
            const uint4* wb = Wl + tid;
            const uint4* tb = (const uint4*)ownpk;
            #pragma unroll
            for (int j = 0; j < 16; ++j) {
                uint4 wq = wb[j * 512];   // lane-consecutive: conflict-free
                uint4 tq = tb[j];         // wave-uniform: broadcast
                D2Q(acc, wq, tq)
            }
        }
        // scatter partial: own quarter -> LDS; others -> exch (fp32 pairs,
        // 64-bit relaxed-agent atomic store = executes at L2)
        {
            const int q = tid >> 7;               // dest part of row `tid`
            const float accp = __shfl_xor(acc, 1);
            if (q == part) {
                ownpart[tid & 127] = acc;
            } else if (!(tid & 1)) {
                const int s = (part < q) ? part : part - 1;
                float2 pr = make_float2(acc, accp);   // rows (tid, tid+1)
                __hip_atomic_store(
                    &exch[((((size_t)batch * 2 + (t & 1)) * 4 + q) * 3 + s) * 64
                          + ((tid & 127) >> 1)],
                    __builtin_bit_cast(unsigned long long, pr),
                    __ATOMIC_RELAXED, __HIP_MEMORY_SCOPE_AGENT);
            }
        }

        // signal: per-wave drain -> LDS arrival -> 8th wave bumps
        asm volatile("s_waitcnt vmcnt(0)" ::: "memory");
        if ((tid & 63) == 0) {
            unsigned a = __hip_atomic_fetch_add(lctr, 1u, __ATOMIC_RELAXED,
                                                __HIP_MEMORY_SCOPE_WORKGROUP);
            if ((a & 7u) == 7u)
                __hip_atomic_fetch_add(gctr, 1u, __ATOMIC_RELAXED,
                                       __HIP_MEMORY_SCOPE_AGENT);
        }
        // wait for all 4 parts' step-t partials
        if (tid == 0) {
            const unsigned tgt = 4u * (unsigned)(t + 1);
            while (__hip_atomic_load(gctr, __ATOMIC_RELAXED,
                                     __HIP_MEMORY_SCOPE_AGENT) < tgt)
                __builtin_amdgcn_s_sleep(1);
        }
        __syncthreads();
        asm volatile("" ::: "memory");

        // ---- tail (wave 0 only): gather 3 partner fp32 pairs via L2 atomics ----
        if (tid < 64) {
            const unsigned long long* eb =
                exch + (((size_t)batch * 2 + (t & 1)) * 4 + part) * 3 * 64;
            unsigned long long u0 = __hip_atomic_load(eb + 0 * 64 + tid,
                                        __ATOMIC_RELAXED, __HIP_MEMORY_SCOPE_AGENT);
            unsigned long long u1 = __hip_atomic_load(eb + 1 * 64 + tid,
                                        __ATOMIC_RELAXED, __HIP_MEMORY_SCOPE_AGENT);
            unsigned long long u2 = __hip_atomic_load(eb + 2 * 64 + tid,
                                        __ATOMIC_RELAXED, __HIP_MEMORY_SCOPE_AGENT);
            float2 p0 = __builtin_bit_cast(float2, u0);
            float2 p1 = __builtin_bit_cast(float2, u1);
            float2 p2 = __builtin_bit_cast(float2, u2);
            float2 own = *reinterpret_cast<const float2*>(ownpart + 2 * tid);
            float d0 = own.x + p0.x + p1.x + p2.x;
            float d1 = own.y + p0.y + p1.y + p2.y;
            hreg.x = 0.9f * hreg.x + 0.1f * (d0 + xv.x);
            hreg.y = 0.9f * hreg.y + 0.1f * (d1 + xv.y);
            const float th0 = fast_tanh(hreg.x), th1 = fast_tanh(hreg.y);
            *reinterpret_cast<float2*>(
                outH + ((size_t)batch * RT + t) * RN + part * 128 + 2 * tid) =
                make_float2(th0, th1);
            ownpk[tid] = pack2(th0, th1);   // next step's phase-A input
        }
        __syncthreads();   // ownpk/ownpart coherence for next phase A
        xv = xn;
    }
}

// one-time: column-slice W -> f16 pairs in exact read order
// Wpk[part*8192 + j*512 + tid] = W[row=tid][128*part + j*8 .. +8)
__global__ void pack_w(const float* __restrict__ W, uint4* __restrict__ Wpk)
{
    int o = blockIdx.x * blockDim.x + threadIdx.x;
    if (o >= 32768) return;
    int part = o >> 13;
    int j    = (o >> 9) & 15;
    int tid  = o & 511;
    const float* s = W + (size_t)tid * RN + part * 128 + j * 8;
    uint4 v;
    v.x = pack2(s[0], s[1]); v.y = pack2(s[2], s[3]);
    v.z = pack2(s[4], s[5]); v.w = pack2(s[6], s[7]);
    Wpk[o] = v;
}

// geometry epilogue: geo[b,t,:] = hidden[b,t,:] @ Gw^T + Gb ; one wave per (b,t)
__global__ void geom_kernel(const float* __restrict__ hid,
                            const float* __restrict__ Gw,
                            const float* __restrict__ Gb,
                            float* __restrict__ geo)
{
    const int wid  = (blockIdx.x * blockDim.x + threadIdx.x) >> 6;
    const int lane = threadIdx.x & 63;
    if (wid >= RB * RT) return;
    const float* rowp = hid + (size_t)wid * RN;
    float g0 = 0.f, g1 = 0.f;
    #pragma unroll
    for (int j = 0; j < 8; ++j) {
        float v = rowp[lane + 64 * j];
        g0 = fmaf(v, Gw[lane + 64 * j], g0);
        g1 = fmaf(v, Gw[RN + lane + 64 * j], g1);
    }
    #pragma unroll
    for (int m = 32; m >= 1; m >>= 1) {
        g0 += __shfl_xor(g0, m);
        g1 += __shfl_xor(g1, m);
    }
    if (lane == 0) {
        geo[(size_t)wid * 2]     = g0 + Gb[0];
        geo[(size_t)wid * 2 + 1] = g1 + Gb[1];
    }
}

// per-launch init: zero counters (ws poisoned once, never re-poisoned ->
// re-init every call; deterministic). exch written-before-read by protocol.
__global__ void init_misc(unsigned* __restrict__ ctr,
                          unsigned* __restrict__ xcdctr)
{
    int i = blockIdx.x * blockDim.x + threadIdx.x;
    if (i < RB * 32) ctr[i] = 0u;
    if (i < 8) xcdctr[i] = 0u;
}

extern "C" void kernel_launch(void* const* d_in, const int* in_sizes, int n_in,
                              void* d_out, int out_size, void* d_ws, size_t ws_size,
                              hipStream_t stream)
{
    const float* h0 = (const float*)d_in[0];
    const float* X  = (const float*)d_in[1];
    const float* W  = (const float*)d_in[2];
    const float* Gw = (const float*)d_in[3];
    const float* Gb = (const float*)d_in[4];

    float* outH = (float*)d_out;
    float* geo  = outH + (size_t)RB * RT * RN;

    unsigned long long* exch = (unsigned long long*)d_ws;  // 64*2*4*3*64 ull = 768 KB
    unsigned* ctr    = (unsigned*)(exch + (size_t)RB * 2 * 4 * 3 * 64);
    unsigned* xcdctr = ctr + RB * 32;
    uint4*    Wpk    = (uint4*)(((uintptr_t)(xcdctr + 8) + 15) & ~(uintptr_t)15);

    (void)hipFuncSetAttribute((const void*)rnn_step_kernel,
                              hipFuncAttributeMaxDynamicSharedMemorySize, SMEM_BYTES);

    pack_w<<<64, 512, 0, stream>>>(W, Wpk);
    init_misc<<<8, 512, 0, stream>>>(ctr, xcdctr);

    void* kargs[] = { (void*)&h0, (void*)&X, (void*)&Wpk,
                      (void*)&outH, (void*)&exch, (void*)&ctr, (void*)&xcdctr };
    (void)hipLaunchCooperativeKernel(rnn_step_kernel, dim3(256), dim3(512),
                                     kargs, SMEM_BYTES, stream);

    geom_kernel<<<(RB * RT * 64 + 255) / 256, 256, 0, stream>>>(outH, Gw, Gb, geo);
}

// Round 19
// 2363.343 us; speedup vs baseline: 1.3049x; 1.0748x over previous
//
#include <hip/hip_runtime.h>
#include <hip/hip_fp16.h>
#include <cmath>

#define RN 512
#define RT 1024
#define RB 64
#define SMEM_COL 131872             // 128KB W + ownpk + ownpart + ctl
#define SMEM_ROW (131072 + 320)     // R15 layout

typedef _Float16 half2v __attribute__((ext_vector_type(2)));

__device__ __forceinline__ float fast_tanh(float x) {
    float e = __expf(2.0f * x);
    return 1.0f - 2.0f / (e + 1.0f);
}
__device__ __forceinline__ unsigned pack2(float a, float b) {   // RNE
    return (unsigned)__half_as_ushort(__float2half(a)) |
           ((unsigned)__half_as_ushort(__float2half(b)) << 16);
}
__device__ __forceinline__ unsigned pkrtz(float a, float b) {
    auto h = __builtin_amdgcn_cvt_pkrtz(a, b);
    return __builtin_bit_cast(unsigned, h);
}
__device__ __forceinline__ float h16lo(unsigned u) {
    return __half2float(__ushort_as_half((unsigned short)(u & 0xffffu)));
}
__device__ __forceinline__ float h16hi(unsigned u) {
    return __half2float(__ushort_as_half((unsigned short)(u >> 16)));
}
__device__ __forceinline__ float dot2(unsigned wa, unsigned tb, float acc) {
    half2v a = __builtin_bit_cast(half2v, wa);
    half2v b = __builtin_bit_cast(half2v, tb);
    return __builtin_amdgcn_fdot2(a, b, acc, false);
}
template <int CTRL>
__device__ __forceinline__ float dpp_add(float x) {
    int p = __builtin_amdgcn_update_dpp(0, __float_as_int(x), CTRL, 0xf, 0xf, true);
    return x + __int_as_float(p);
}
__device__ __forceinline__ float red16(float x) {
    x = dpp_add<0xB1>(x);
    x = dpp_add<0x4E>(x);
    x = dpp_add<0x141>(x);
    x = dpp_add<0x140>(x);
    return x;
}
#define D2Q(acc, wq, tq) \
    acc = dot2((wq).x, (tq).x, acc); acc = dot2((wq).y, (tq).y, acc); \
    acc = dot2((wq).z, (tq).z, acc); acc = dot2((wq).w, (tq).w, acc);

// ---------------- FAST PATH: column-split, fresh-address L2 exchange --------
// Block holds W[0:512, 128p:+128) (f16 LDS, read order [j][tid]); the entire
// matvec (row `tid`, 128-k band, th = OWN rows from ownpk) is pre-barrier.
// Partials exchanged as f16-RNE pairs via PLAIN stores to a t-INDEXED buffer
// (every address written once, read once -> producer's dirty line in the
// shared XCD L2 is read by the same-XCD consumer: the R13/R15-proven channel;
// NO atomics on the data path -- R18 showed agent atomics run at L3).
__global__ void __launch_bounds__(512, 1) rnn_col_kernel(
    const float* __restrict__ h0,
    const float* __restrict__ X,
    const uint4* __restrict__ Wpk,     // [4 part][16 j][512 tid]
    float* __restrict__ outH,
    unsigned* __restrict__ exch,       // [b][t][4 dest][3 src][64] u32
    unsigned* __restrict__ ctr,
    unsigned* __restrict__ xcdctr)
{
    extern __shared__ unsigned char smem[];
    uint4*    Wl      = (uint4*)smem;                    // 8192 uint4 = 128 KB
    unsigned* ownpk   = (unsigned*)(smem + 131072);      // 64 u32 th pairs
    float*    ownpart = (float*)(smem + 131072 + 256);   // 128 f32
    int*      bc      = (int*)(smem + 131072 + 768);
    unsigned* lctr    = (unsigned*)(smem + 131072 + 776);

    const int tid = threadIdx.x;
    if (tid == 0) {
        unsigned xcd;
        asm volatile("s_getreg_b32 %0, hwreg(HW_REG_XCC_ID)" : "=s"(xcd));
        xcd &= 7u;
        unsigned rank = __hip_atomic_fetch_add(&xcdctr[xcd], 1u,
                            __ATOMIC_RELAXED, __HIP_MEMORY_SCOPE_AGENT) & 31u;
        int slot = (int)(xcd * 32u + rank);
        bc[0] = slot >> 2;                    // batch
        bc[1] = slot & 3;                     // part
        *lctr = 0u;
    }
    __syncthreads();
    const int batch = bc[0], part = bc[1];

    {
        const uint4* src = Wpk + part * 8192;
        #pragma unroll
        for (int i = 0; i < 16; ++i)
            Wl[i * 512 + tid] = src[i * 512 + tid];
    }

    float2 hreg = {0.f, 0.f}, xv = {0.f, 0.f};
    if (tid < 64) {
        hreg = *reinterpret_cast<const float2*>(h0 + part * 128 + 2 * tid);
        ownpk[tid] = pack2(tanhf(hreg.x), tanhf(hreg.y));
        xv = *reinterpret_cast<const float2*>(
            X + (size_t)batch * RT * RN + part * 128 + 2 * tid);
    }

    unsigned* gctr = ctr + batch * 32;
    __syncthreads();

    #pragma unroll 1
    for (int t = 0; t < RT; ++t) {
        float2 xn = {0.f, 0.f};
        if (tid < 64) {
            const int tn = (t + 1 < RT) ? t + 1 : t;
            xn = *reinterpret_cast<const float2*>(
                X + ((size_t)batch * RT + tn) * RN + part * 128 + 2 * tid);
        }

        // phase A: full dot for global row `tid` (partner-independent)
        float acc = 0.f;
        {
            const uint4* wb = Wl + tid;
            const uint4* tb = (const uint4*)ownpk;
            #pragma unroll
            for (int j = 0; j < 16; ++j) {
                uint4 wq = wb[j * 512];
                uint4 tq = tb[j];
                D2Q(acc, wq, tq)
            }
        }
        // scatter: own quarter -> LDS; others -> fresh exch (plain store)
        {
            const float accp = __shfl_xor(acc, 1);
            const int q = tid >> 7;
            if (q == part) {
                ownpart[tid & 127] = acc;
            } else if (!(tid & 1)) {
                const int s = (part < q) ? part : part - 1;
                exch[(((size_t)batch * RT + t) * 4 + q) * 192
                     + s * 64 + ((tid & 127) >> 1)] = pack2(acc, accp);
            }
        }

        asm volatile("s_waitcnt vmcnt(0)" ::: "memory");   // stores in XCD L2
        if ((tid & 63) == 0) {
            unsigned a = __hip_atomic_fetch_add(lctr, 1u, __ATOMIC_RELAXED,
                                                __HIP_MEMORY_SCOPE_WORKGROUP);
            if ((a & 7u) == 7u)
                __hip_atomic_fetch_add(gctr, 1u, __ATOMIC_RELAXED,
                                       __HIP_MEMORY_SCOPE_AGENT);
        }
        if (tid == 0) {
            const unsigned tgt = 4u * (unsigned)(t + 1);
            while (__hip_atomic_load(gctr, __ATOMIC_RELAXED,
                                     __HIP_MEMORY_SCOPE_AGENT) < tgt)
                __builtin_amdgcn_s_sleep(1);
        }
        __syncthreads();
        asm volatile("" ::: "memory");

        // tail (wave 0): gather 3 partner pairs via plain L2 loads (fresh)
        if (tid < 64) {
            const unsigned* eb =
                exch + (((size_t)batch * RT + t) * 4 + part) * 192;
            unsigned u0 = eb[0 * 64 + tid];
            unsigned u1 = eb[1 * 64 + tid];
            unsigned u2 = eb[2 * 64 + tid];
            float2 own = *reinterpret_cast<const float2*>(ownpart + 2 * tid);
            float d0 = own.x + h16lo(u0) + h16lo(u1) + h16lo(u2);
            float d1 = own.y + h16hi(u0) + h16hi(u1) + h16hi(u2);
            hreg.x = 0.9f * hreg.x + 0.1f * (d0 + xv.x);
            hreg.y = 0.9f * hreg.y + 0.1f * (d1 + xv.y);
            const float th0 = fast_tanh(hreg.x), th1 = fast_tanh(hreg.y);
            *reinterpret_cast<float2*>(
                outH + ((size_t)batch * RT + t) * RN + part * 128 + 2 * tid) =
                make_float2(th0, th1);
            ownpk[tid] = pack2(th0, th1);
        }
        __syncthreads();
        xv = xn;
    }
}

// Wpk (column order): Wpk[part*8192 + j*512 + tid] = W[tid][128p + 8j .. +8)
__global__ void pack_w_col(const float* __restrict__ W, uint4* __restrict__ Wpk)
{
    int o = blockIdx.x * blockDim.x + threadIdx.x;
    if (o >= 32768) return;
    int part = o >> 13;
    int j    = (o >> 9) & 15;
    int tid  = o & 511;
    const float* s = W + (size_t)tid * RN + part * 128 + j * 8;
    uint4 v;
    v.x = pack2(s[0], s[1]); v.y = pack2(s[2], s[3]);
    v.z = pack2(s[4], s[5]); v.w = pack2(s[6], s[7]);
    Wpk[o] = v;
}

// ---------------- FALLBACK: R15 champion (verbatim; 2034us proven) ----------
__global__ void __launch_bounds__(512, 1) rnn_row_kernel(
    const float* __restrict__ h0,
    const float* __restrict__ X,
    const uint4* __restrict__ Wpk,     // [4 part][4 band][4 i][512 tid]
    const float* __restrict__ tanh0,
    float* __restrict__ outH,
    unsigned* __restrict__ ctr,
    unsigned* __restrict__ xcdctr)
{
    extern __shared__ unsigned char smem[];
    uint4*    Wl    = (uint4*)smem;
    unsigned* ownpk = (unsigned*)(smem + 131072);
    int*      bc    = (int*)(smem + 131072 + 256);
    unsigned* lctr  = (unsigned*)(smem + 131072 + 264);

    const int tid = threadIdx.x;
    if (tid == 0) {
        unsigned xcd;
        asm volatile("s_getreg_b32 %0, hwreg(HW_REG_XCC_ID)" : "=s"(xcd));
        xcd &= 7u;
        unsigned rank = __hip_atomic_fetch_add(&xcdctr[xcd], 1u,
                            __ATOMIC_RELAXED, __HIP_MEMORY_SCOPE_AGENT) & 31u;
        int slot = (int)(xcd * 32u + rank);
        bc[0] = slot >> 2;
        bc[1] = slot & 3;
        *lctr = 0u;
    }
    __syncthreads();
    const int batch = bc[0], part = bc[1];

    {
        const uint4* src = Wpk + part * 8192;
        #pragma unroll
        for (int i = 0; i < 16; ++i)
            Wl[i * 512 + tid] = src[i * 512 + tid];
    }

    const int rg = tid >> 4;
    const int kc = tid & 15;
    const int row0 = part * 128 + rg * 4;

    float4 h = {0, 0, 0, 0};
    float4 xv = {0, 0, 0, 0};
    if (kc == 0) {
        h = *reinterpret_cast<const float4*>(h0 + row0);
        float t0 = tanhf(h.x), t1 = tanhf(h.y), t2 = tanhf(h.z), t3 = tanhf(h.w);
        ownpk[2 * rg]     = pack2(t0, t1);
        ownpk[2 * rg + 1] = pack2(t2, t3);
        xv = *reinterpret_cast<const float4*>(&X[(size_t)batch * RT * RN + row0]);
    }

    unsigned* gctr = ctr + batch * 32;
    __syncthreads();

    #pragma unroll 1
    for (int t = 0; t < RT; ++t) {
        float4 xn = {0, 0, 0, 0};
        if (kc == 0) {
            const int tn = (t + 1 < RT) ? t + 1 : t;
            xn = *reinterpret_cast<const float4*>(&X[((size_t)batch * RT + tn) * RN + row0]);
        }

        float acc0 = 0.f, acc1 = 0.f, acc2 = 0.f, acc3 = 0.f;
        {
            uint4 th = *reinterpret_cast<const uint4*>(&ownpk[4 * kc]);
            uint4 wq0 = Wl[(part * 4 + 0) * 512 + tid];
            uint4 wq1 = Wl[(part * 4 + 1) * 512 + tid];
            uint4 wq2 = Wl[(part * 4 + 2) * 512 + tid];
            uint4 wq3 = Wl[(part * 4 + 3) * 512 + tid];
            D2Q(acc0, wq0, th) D2Q(acc1, wq1, th)
            D2Q(acc2, wq2, th) D2Q(acc3, wq3, th)
        }

        if (tid == 0 && t > 0) {
            const unsigned tgt = 4u * (unsigned)t;
            while (__hip_atomic_load(gctr, __ATOMIC_RELAXED,
                                     __HIP_MEMORY_SCOPE_AGENT) < tgt)
                __builtin_amdgcn_s_sleep(1);
        }
        __syncthreads();

        const float* srcR = (t == 0) ? tanh0
            : &outH[((size_t)batch * RT + (t - 1)) * RN];
        #pragma unroll
        for (int bb = 0; bb < 3; ++bb) {
            const int b = bb + (bb >= part);
            const int ko = b * 128 + kc * 8;
            float4 f0 = *reinterpret_cast<const float4*>(srcR + ko);
            float4 f1 = *reinterpret_cast<const float4*>(srcR + ko + 4);
            uint4 tv = make_uint4(pkrtz(f0.x, f0.y), pkrtz(f0.z, f0.w),
                                  pkrtz(f1.x, f1.y), pkrtz(f1.z, f1.w));
            uint4 wq0 = Wl[(b * 4 + 0) * 512 + tid];
            uint4 wq1 = Wl[(b * 4 + 1) * 512 + tid];
            uint4 wq2 = Wl[(b * 4 + 2) * 512 + tid];
            uint4 wq3 = Wl[(b * 4 + 3) * 512 + tid];
            D2Q(acc0, wq0, tv) D2Q(acc1, wq1, tv)
            D2Q(acc2, wq2, tv) D2Q(acc3, wq3, tv)
        }

        acc0 = red16(acc0); acc1 = red16(acc1);
        acc2 = red16(acc2); acc3 = red16(acc3);

        if (kc == 0) {
            h.x = 0.9f * h.x + 0.1f * (acc0 + xv.x);
            h.y = 0.9f * h.y + 0.1f * (acc1 + xv.y);
            h.z = 0.9f * h.z + 0.1f * (acc2 + xv.z);
            h.w = 0.9f * h.w + 0.1f * (acc3 + xv.w);
            float t0 = fast_tanh(h.x), t1 = fast_tanh(h.y);
            float t2 = fast_tanh(h.z), t3 = fast_tanh(h.w);
            *reinterpret_cast<float4*>(&outH[((size_t)batch * RT + t) * RN + row0]) =
                make_float4(t0, t1, t2, t3);
            ownpk[2 * rg]     = pack2(t0, t1);
            ownpk[2 * rg + 1] = pack2(t2, t3);
        }

        asm volatile("s_waitcnt vmcnt(0)" ::: "memory");
        if ((tid & 63) == 0) {
            unsigned a = __hip_atomic_fetch_add(lctr, 1u, __ATOMIC_RELAXED,
                                                __HIP_MEMORY_SCOPE_WORKGROUP);
            if ((a & 7u) == 7u)
                __hip_atomic_fetch_add(gctr, 1u, __ATOMIC_RELAXED,
                                       __HIP_MEMORY_SCOPE_AGENT);
        }
        __syncthreads();
        xv = xn;
    }
}

// Wpk (row order): Wpk[part*8192+(b*4+i)*512+tid] = W[128p+(tid>>4)*4+i][128b+(tid&15)*8..+8)
__global__ void pack_w_row(const float* __restrict__ W, uint4* __restrict__ Wpk)
{
    int o = blockIdx.x * blockDim.x + threadIdx.x;
    if (o >= 32768) return;
    int part = o >> 13;
    int b    = (o >> 11) & 3;
    int i    = (o >> 9) & 3;
    int tid  = o & 511;
    int row  = part * 128 + (tid >> 4) * 4 + i;
    int k0   = b * 128 + (tid & 15) * 8;
    const float* s = W + (size_t)row * RN + k0;
    uint4 v;
    v.x = pack2(s[0], s[1]); v.y = pack2(s[2], s[3]);
    v.z = pack2(s[4], s[5]); v.w = pack2(s[6], s[7]);
    Wpk[o] = v;
}

// geometry epilogue
__global__ void geom_kernel(const float* __restrict__ hid,
                            const float* __restrict__ Gw,
                            const float* __restrict__ Gb,
                            float* __restrict__ geo)
{
    const int wid  = (blockIdx.x * blockDim.x + threadIdx.x) >> 6;
    const int lane = threadIdx.x & 63;
    if (wid >= RB * RT) return;
    const float* rowp = hid + (size_t)wid * RN;
    float g0 = 0.f, g1 = 0.f;
    #pragma unroll
    for (int j = 0; j < 8; ++j) {
        float v = rowp[lane + 64 * j];
        g0 = fmaf(v, Gw[lane + 64 * j], g0);
        g1 = fmaf(v, Gw[RN + lane + 64 * j], g1);
    }
    #pragma unroll
    for (int m = 32; m >= 1; m >>= 1) {
        g0 += __shfl_xor(g0, m);
        g1 += __shfl_xor(g1, m);
    }
    if (lane == 0) {
        geo[(size_t)wid * 2]     = g0 + Gb[0];
        geo[(size_t)wid * 2 + 1] = g1 + Gb[1];
    }
}

__global__ void init_misc(const float* __restrict__ h0,
                          float* __restrict__ tanh0,
                          unsigned* __restrict__ ctr,
                          unsigned* __restrict__ xcdctr)
{
    int i = blockIdx.x * blockDim.x + threadIdx.x;
    if (i < RN) tanh0[i] = tanhf(h0[i]);
    if (i < RB * 32) ctr[i] = 0u;
    if (i < 8) xcdctr[i] = 0u;
}

extern "C" void kernel_launch(void* const* d_in, const int* in_sizes, int n_in,
                              void* d_out, int out_size, void* d_ws, size_t ws_size,
                              hipStream_t stream)
{
    const float* h0 = (const float*)d_in[0];
    const float* X  = (const float*)d_in[1];
    const float* W  = (const float*)d_in[2];
    const float* Gw = (const float*)d_in[3];
    const float* Gb = (const float*)d_in[4];

    float* outH = (float*)d_out;
    float* geo  = outH + (size_t)RB * RT * RN;

    const size_t exch_u32 = (size_t)RB * RT * 4 * 192;          // 50,331,648
    const size_t need_fast = exch_u32 * 4 + (RN + RB * 32 + 8) * 4 + 64 + 524288;

    if (ws_size >= need_fast) {
        // -------- fast path: column-split + fresh-address L2 exchange --------
        unsigned* exch   = (unsigned*)d_ws;                      // 201.3 MB
        float*    tanh0  = (float*)(exch + exch_u32);            // unused here, kept for layout
        unsigned* ctr    = (unsigned*)(tanh0 + RN);
        unsigned* xcdctr = ctr + RB * 32;
        uint4*    Wpk    = (uint4*)(((uintptr_t)(xcdctr + 8) + 63) & ~(uintptr_t)63);

        (void)hipFuncSetAttribute((const void*)rnn_col_kernel,
                                  hipFuncAttributeMaxDynamicSharedMemorySize, SMEM_COL);
        pack_w_col<<<64, 512, 0, stream>>>(W, Wpk);
        init_misc<<<8, 512, 0, stream>>>(h0, tanh0, ctr, xcdctr);

        void* kargs[] = { (void*)&h0, (void*)&X, (void*)&Wpk,
                          (void*)&outH, (void*)&exch, (void*)&ctr, (void*)&xcdctr };
        (void)hipLaunchCooperativeKernel(rnn_col_kernel, dim3(256), dim3(512),
                                         kargs, SMEM_COL, stream);
    } else {
        // -------- fallback: R15 champion (proven 2034us) --------
        float*    tanh0  = (float*)d_ws;
        unsigned* ctr    = (unsigned*)d_ws + RN;
        unsigned* xcdctr = ctr + RB * 32;
        uint4*    Wpk    = (uint4*)(((uintptr_t)(xcdctr + 8) + 63) & ~(uintptr_t)63);

        (void)hipFuncSetAttribute((const void*)rnn_row_kernel,
                                  hipFuncAttributeMaxDynamicSharedMemorySize, SMEM_ROW);
        pack_w_row<<<64, 512, 0, stream>>>(W, Wpk);
        init_misc<<<8, 512, 0, stream>>>(h0, tanh0, ctr, xcdctr);

        void* kargs[] = { (void*)&h0, (void*)&X, (void*)&Wpk, (void*)&tanh0,
                          (void*)&outH, (void*)&ctr, (void*)&xcdctr };
        (void)hipLaunchCooperativeKernel(rnn_row_kernel, dim3(256), dim3(512),
                                         kargs, SMEM_ROW, stream);
    }

    geom_kernel<<<(RB * RT * 64 + 255) / 256, 256, 0, stream>>>(outH, Gw, Gb, geo);
}

// Round 20
// 1864.986 us; speedup vs baseline: 1.6536x; 1.2672x over previous
//
#include <hip/hip_runtime.h>
#include <hip/hip_fp16.h>
#include <cmath>

#define RN 512
#define RT 1024
#define RB 64
#define SMEM_BYTES 86016   // tiny real use; pad forces exactly 1 block/CU

typedef _Float16 half2v __attribute__((ext_vector_type(2)));

__device__ __forceinline__ float fast_tanh(float x) {
    float e = __expf(2.0f * x);
    return 1.0f - 2.0f / (e + 1.0f);
}
__device__ __forceinline__ unsigned pack2(float a, float b) {   // RNE
    return (unsigned)__half_as_ushort(__float2half(a)) |
           ((unsigned)__half_as_ushort(__float2half(b)) << 16);
}
__device__ __forceinline__ unsigned pkrtz(float a, float b) {
    auto h = __builtin_amdgcn_cvt_pkrtz(a, b);
    return __builtin_bit_cast(unsigned, h);
}
__device__ __forceinline__ float dot2(unsigned wa, unsigned tb, float acc) {
    half2v a = __builtin_bit_cast(half2v, wa);
    half2v b = __builtin_bit_cast(half2v, tb);
    return __builtin_amdgcn_fdot2(a, b, acc, false);
}
template <int CTRL>
__device__ __forceinline__ float dpp_add(float x) {
    int p = __builtin_amdgcn_update_dpp(0, __float_as_int(x), CTRL, 0xf, 0xf, true);
    return x + __int_as_float(p);
}
__device__ __forceinline__ float red16(float x) {
    x = dpp_add<0xB1>(x);   // quad_perm xor1
    x = dpp_add<0x4E>(x);   // quad_perm xor2
    x = dpp_add<0x141>(x);  // row_half_mirror
    x = dpp_add<0x140>(x);  // row_mirror
    return x;
}
#define D2Q(acc, wq, tq) \
    acc = dot2((wq).x, (tq).x, acc); acc = dot2((wq).y, (tq).y, acc); \
    acc = dot2((wq).z, (tq).z, acc); acc = dot2((wq).w, (tq).w, acc);

#define PIN4(v) asm volatile("" : "+v"((v).x), "+v"((v).y), "+v"((v).z), "+v"((v).w));

// Load the 4 uint4 of rotated band bb (b = (part+bb)&3): compile-time register
// names, runtime only in the ADDRESS.
#define LOADB(bb) { \
    const int b_ = (part + (bb)) & 3; \
    w##bb##_0 = wsrc[(b_ * 4 + 0) * 512]; PIN4(w##bb##_0) \
    w##bb##_1 = wsrc[(b_ * 4 + 1) * 512]; PIN4(w##bb##_1) \
    w##bb##_2 = wsrc[(b_ * 4 + 2) * 512]; PIN4(w##bb##_2) \
    w##bb##_3 = wsrc[(b_ * 4 + 3) * 512]; PIN4(w##bb##_3) }

#define DOTB(bb, tv) \
    D2Q(acc0, w##bb##_0, tv) D2Q(acc1, w##bb##_1, tv) \
    D2Q(acc2, w##bb##_2, tv) D2Q(acc3, w##bb##_3, tv)

// R15 champion skeleton (2034us proven: same-XCD quads via XCC_ID rank,
// phase A before relaxed tid0 poll, fp32-outH exchange, DPP reduce, signal
// hoist) with ONE change: W is REGISTER-RESIDENT. Each thread's 16 W uint4
// (4 bands x 4 rows x 8k f16) are loop-invariant -> 64 VGPRs, loaded once
// from Wpk in part-ROTATED order (w0_* = own band) so every register index
// is compile-time (rule: no runtime indexing into registers). At
// __launch_bounds__(512,1) the cap is 256 VGPR/thread -- the R2/R3 spills
// were under the (512,2) 128-cap. This deletes the 128KB/step LDS W sweep
// (~1100-1500cy, the largest non-sync cost). LDS keeps only ownpk (256B) +
// ctl, padded to 86KB so exactly 1 block/CU (rank-math invariant).
__global__ void __launch_bounds__(512, 1) rnn_step_kernel(
    const float* __restrict__ h0,
    const float* __restrict__ X,
    const uint4* __restrict__ Wpk,     // [4 part][4 band][4 i][512 tid]
    const float* __restrict__ tanh0,
    float* __restrict__ outH,
    unsigned* __restrict__ ctr,
    unsigned* __restrict__ xcdctr)
{
    extern __shared__ unsigned char smem[];
    unsigned* ownpk = (unsigned*)smem;               // 64 u32: packed th pairs
    int*      bc    = (int*)(smem + 256);
    unsigned* lctr  = (unsigned*)(smem + 264);

    const int tid = threadIdx.x;
    if (tid == 0) {
        unsigned xcd;
        asm volatile("s_getreg_b32 %0, hwreg(HW_REG_XCC_ID)" : "=s"(xcd));
        xcd &= 7u;
        unsigned rank = __hip_atomic_fetch_add(&xcdctr[xcd], 1u,
                            __ATOMIC_RELAXED, __HIP_MEMORY_SCOPE_AGENT) & 31u;
        int slot = (int)(xcd * 32u + rank);   // 0..255
        bc[0] = slot >> 2;                    // batch 0..63
        bc[1] = slot & 3;                     // part  0..3
        *lctr = 0u;
    }
    __syncthreads();
    const int batch = bc[0], part = bc[1];

    // ---- W fragment -> 16 named uint4 registers (rotated: w0_* = own band) ----
    uint4 w0_0, w0_1, w0_2, w0_3;
    uint4 w1_0, w1_1, w1_2, w1_3;
    uint4 w2_0, w2_1, w2_2, w2_3;
    uint4 w3_0, w3_1, w3_2, w3_3;
    {
        const uint4* wsrc = Wpk + part * 8192 + tid;
        LOADB(0) LOADB(1) LOADB(2) LOADB(3)
    }

    const int rg = tid >> 4;                  // 0..31 : 4-row group
    const int kc = tid & 15;                  // 0..15 : 8-k sub-chunk per band
    const int row0 = part * 128 + rg * 4;

    float4 h = {0, 0, 0, 0};
    float4 xv = {0, 0, 0, 0};
    if (kc == 0) {
        h = *reinterpret_cast<const float4*>(h0 + row0);
        float t0 = tanhf(h.x), t1 = tanhf(h.y), t2 = tanhf(h.z), t3 = tanhf(h.w);
        ownpk[2 * rg]     = pack2(t0, t1);
        ownpk[2 * rg + 1] = pack2(t2, t3);
        xv = *reinterpret_cast<const float4*>(&X[(size_t)batch * RT * RN + row0]);
    }

    unsigned* gctr = ctr + batch * 32;        // 128B line per quad
    __syncthreads();                          // ownpk staged

    #pragma unroll 1
    for (int t = 0; t < RT; ++t) {
        // 2-deep X prefetch: issue X[t+1] now; full-step window to complete
        float4 xn = {0, 0, 0, 0};
        if (kc == 0) {
            const int tn = (t + 1 < RT) ? t + 1 : t;
            xn = *reinterpret_cast<const float4*>(&X[((size_t)batch * RT + tn) * RN + row0]);
        }

        // ---- phase A: own band from registers + ownpk (no partner dep) ----
        float acc0 = 0.f, acc1 = 0.f, acc2 = 0.f, acc3 = 0.f;
        {
            uint4 th = *reinterpret_cast<const uint4*>(&ownpk[4 * kc]);
            DOTB(0, th)
        }

        // ---- wait for all 4 parts of step t-1 (tid0 poll + barrier bcast) ----
        if (tid == 0 && t > 0) {
            const unsigned tgt = 4u * (unsigned)t;
            while (__hip_atomic_load(gctr, __ATOMIC_RELAXED,
                                     __HIP_MEMORY_SCOPE_AGENT) < tgt)
                __builtin_amdgcn_s_sleep(1);
        }
        __syncthreads();

        // ---- phase B: 3 partner bands, fp32 outH -> pkrtz -> register dots ----
        const float* srcR = (t == 0) ? tanh0
            : &outH[((size_t)batch * RT + (t - 1)) * RN];
        {
            const int b1 = (part + 1) & 3;
            const int ko = b1 * 128 + kc * 8;
            float4 f0 = *reinterpret_cast<const float4*>(srcR + ko);
            float4 f1 = *reinterpret_cast<const float4*>(srcR + ko + 4);
            uint4 tv = make_uint4(pkrtz(f0.x, f0.y), pkrtz(f0.z, f0.w),
                                  pkrtz(f1.x, f1.y), pkrtz(f1.z, f1.w));
            DOTB(1, tv)
        }
        {
            const int b2 = (part + 2) & 3;
            const int ko = b2 * 128 + kc * 8;
            float4 f0 = *reinterpret_cast<const float4*>(srcR + ko);
            float4 f1 = *reinterpret_cast<const float4*>(srcR + ko + 4);
            uint4 tv = make_uint4(pkrtz(f0.x, f0.y), pkrtz(f0.z, f0.w),
                                  pkrtz(f1.x, f1.y), pkrtz(f1.z, f1.w));
            DOTB(2, tv)
        }
        {
            const int b3 = (part + 3) & 3;
            const int ko = b3 * 128 + kc * 8;
            float4 f0 = *reinterpret_cast<const float4*>(srcR + ko);
            float4 f1 = *reinterpret_cast<const float4*>(srcR + ko + 4);
            uint4 tv = make_uint4(pkrtz(f0.x, f0.y), pkrtz(f0.z, f0.w),
                                  pkrtz(f1.x, f1.y), pkrtz(f1.z, f1.w));
            DOTB(3, tv)
        }

        // ---- 16-lane all-reduce in VALU (DPP) ----
        acc0 = red16(acc0); acc1 = red16(acc1);
        acc2 = red16(acc2); acc3 = red16(acc3);

        if (kc == 0) {
            h.x = 0.9f * h.x + 0.1f * (acc0 + xv.x);
            h.y = 0.9f * h.y + 0.1f * (acc1 + xv.y);
            h.z = 0.9f * h.z + 0.1f * (acc2 + xv.z);
            h.w = 0.9f * h.w + 0.1f * (acc3 + xv.w);
            float t0 = fast_tanh(h.x), t1 = fast_tanh(h.y);
            float t2 = fast_tanh(h.z), t3 = fast_tanh(h.w);
            *reinterpret_cast<float4*>(&outH[((size_t)batch * RT + t) * RN + row0]) =
                make_float4(t0, t1, t2, t3);
            ownpk[2 * rg]     = pack2(t0, t1);
            ownpk[2 * rg + 1] = pack2(t2, t3);
        }

        // ---- signal hoist: per-wave drain -> LDS arrival -> 8th wave fires ----
        asm volatile("s_waitcnt vmcnt(0)" ::: "memory");   // stores in XCD L2
        if ((tid & 63) == 0) {
            unsigned a = __hip_atomic_fetch_add(lctr, 1u, __ATOMIC_RELAXED,
                                                __HIP_MEMORY_SCOPE_WORKGROUP);
            if ((a & 7u) == 7u)
                __hip_atomic_fetch_add(gctr, 1u, __ATOMIC_RELAXED,
                                       __HIP_MEMORY_SCOPE_AGENT);
        }
        __syncthreads();   // ownpk coherence for next step's phase A
        xv = xn;
    }
}

// one-time: W -> f16 pairs in exact per-read order
// Wpk[part*8192 + (b*4+i)*512 + tid] = W[part*128+(tid>>4)*4+i][b*128+(tid&15)*8 ..+8]
__global__ void pack_w(const float* __restrict__ W, uint4* __restrict__ Wpk)
{
    int o = blockIdx.x * blockDim.x + threadIdx.x;
    if (o >= 32768) return;
    int part = o >> 13;
    int b    = (o >> 11) & 3;
    int i    = (o >> 9) & 3;
    int tid  = o & 511;
    int row  = part * 128 + (tid >> 4) * 4 + i;
    int k0   = b * 128 + (tid & 15) * 8;
    const float* s = W + (size_t)row * RN + k0;
    uint4 v;
    v.x = pack2(s[0], s[1]); v.y = pack2(s[2], s[3]);
    v.z = pack2(s[4], s[5]); v.w = pack2(s[6], s[7]);
    Wpk[o] = v;
}

// geometry epilogue: geo[b,t,:] = hidden[b,t,:] @ Gw^T + Gb ; one wave per (b,t)
__global__ void geom_kernel(const float* __restrict__ hid,
                            const float* __restrict__ Gw,
                            const float* __restrict__ Gb,
                            float* __restrict__ geo)
{
    const int wid  = (blockIdx.x * blockDim.x + threadIdx.x) >> 6;
    const int lane = threadIdx.x & 63;
    if (wid >= RB * RT) return;
    const float* rowp = hid + (size_t)wid * RN;
    float g0 = 0.f, g1 = 0.f;
    #pragma unroll
    for (int j = 0; j < 8; ++j) {
        float v = rowp[lane + 64 * j];
        g0 = fmaf(v, Gw[lane + 64 * j], g0);
        g1 = fmaf(v, Gw[RN + lane + 64 * j], g1);
    }
    #pragma unroll
    for (int m = 32; m >= 1; m >>= 1) {
        g0 += __shfl_xor(g0, m);
        g1 += __shfl_xor(g1, m);
    }
    if (lane == 0) {
        geo[(size_t)wid * 2]     = g0 + Gb[0];
        geo[(size_t)wid * 2 + 1] = g1 + Gb[1];
    }
}

// per-launch init: tanh(h0) table + zero counters (ws poisoned once, never
// re-poisoned -> re-init every call; deterministic)
__global__ void init_misc(const float* __restrict__ h0,
                          float* __restrict__ tanh0,
                          unsigned* __restrict__ ctr,
                          unsigned* __restrict__ xcdctr)
{
    int i = blockIdx.x * blockDim.x + threadIdx.x;
    if (i < RN) tanh0[i] = tanhf(h0[i]);
    if (i < RB * 32) ctr[i] = 0u;
    if (i < 8) xcdctr[i] = 0u;
}

extern "C" void kernel_launch(void* const* d_in, const int* in_sizes, int n_in,
                              void* d_out, int out_size, void* d_ws, size_t ws_size,
                              hipStream_t stream)
{
    const float* h0 = (const float*)d_in[0];
    const float* X  = (const float*)d_in[1];
    const float* W  = (const float*)d_in[2];
    const float* Gw = (const float*)d_in[3];
    const float* Gb = (const float*)d_in[4];

    float* outH = (float*)d_out;
    float* geo  = outH + (size_t)RB * RT * RN;

    float*    tanh0  = (float*)d_ws;                  // 512 f32
    unsigned* ctr    = (unsigned*)d_ws + RN;          // 64*32 u32
    unsigned* xcdctr = ctr + RB * 32;                 // 8 u32
    uint4*    Wpk    = (uint4*)(((uintptr_t)(xcdctr + 8) + 63) & ~(uintptr_t)63);

    (void)hipFuncSetAttribute((const void*)rnn_step_kernel,
                              hipFuncAttributeMaxDynamicSharedMemorySize, SMEM_BYTES);

    pack_w<<<64, 512, 0, stream>>>(W, Wpk);
    init_misc<<<8, 512, 0, stream>>>(h0, tanh0, ctr, xcdctr);

    void* kargs[] = { (void*)&h0, (void*)&X, (void*)&Wpk, (void*)&tanh0,
                      (void*)&outH, (void*)&ctr, (void*)&xcdctr };
    (void)hipLaunchCooperativeKernel(rnn_step_kernel, dim3(256), dim3(512),
                                     kargs, SMEM_BYTES, stream);

    geom_kernel<<<(RB * RT * 64 + 255) / 256, 256, 0, stream>>>(outH, Gw, Gb, geo);
}